// Round 2
// baseline (429.699 us; speedup 1.0000x reference)
//
#include <hip/hip_runtime.h>

// Haar DWT 2x2 on x: (4, 64, 512, 512) f32 -> out: (4, 256, 256, 256) f32
// out[b][4*c+k][i][j], k in {ll, lh, hl, hh}
// Memory-bound: 256 MB in + 256 MB out. One thread = 1 (b,c,i) x 2 output cols.

__global__ __launch_bounds__(256) void haar_dwt_kernel(const float* __restrict__ x,
                                                       float* __restrict__ out) {
    const int t  = blockIdx.x * 256 + threadIdx.x;
    const int jv = t & 127;          // output col-pair index: cols 2*jv, 2*jv+1
    const int i  = (t >> 7) & 255;   // output row
    const int bc = t >> 15;          // b*64 + c, in [0, 256)

    // Input rows 2i and 2i+1 of plane bc (512x512 floats per plane).
    const float* plane = x + (size_t)bc * (512 * 512);
    const float4* row0 = reinterpret_cast<const float4*>(plane + (2 * i) * 512) + jv;
    const float4* row1 = row0 + 128;  // +512 floats = next row

    const float4 r0 = *row0;  // {a0, b0, a1, b1}  (even/odd cols of top row)
    const float4 r1 = *row1;  // {c0, d0, c1, d1}  (even/odd cols of bottom row)

    const float half = 0.5f;
    float2 ll, lh, hl, hh;
    ll.x = (r0.x + r0.y + r1.x + r1.y) * half;
    lh.x = (r0.x - r0.y + r1.x - r1.y) * half;
    hl.x = (r0.x + r0.y - r1.x - r1.y) * half;
    hh.x = (r0.x - r0.y - r1.x + r1.y) * half;
    ll.y = (r0.z + r0.w + r1.z + r1.w) * half;
    lh.y = (r0.z - r0.w + r1.z - r1.w) * half;
    hl.y = (r0.z + r0.w - r1.z - r1.w) * half;
    hh.y = (r0.z - r0.w - r1.z + r1.w) * half;

    // Output: channel = 4*bc + k, each plane 256x256 floats.
    const size_t obase = ((size_t)(4 * bc) * 256 + i) * 256 + 2 * jv;
    float* o = out + obase;
    *reinterpret_cast<float2*>(o)                 = ll;
    *reinterpret_cast<float2*>(o + 256 * 256)     = lh;
    *reinterpret_cast<float2*>(o + 2 * 256 * 256) = hl;
    *reinterpret_cast<float2*>(o + 3 * 256 * 256) = hh;
}

extern "C" void kernel_launch(void* const* d_in, const int* in_sizes, int n_in,
                              void* d_out, int out_size, void* d_ws, size_t ws_size,
                              hipStream_t stream) {
    const float* x = (const float*)d_in[0];
    float* out = (float*)d_out;
    // total threads = 4*64*256*128 = 8,388,608 -> 32768 blocks of 256 (exact)
    haar_dwt_kernel<<<32768, 256, 0, stream>>>(x, out);
}

// Round 10
// 413.986 us; speedup vs baseline: 1.0380x; 1.0380x over previous
//
#include <hip/hip_runtime.h>

// Haar DWT 2x2 on x: (4, 64, 512, 512) f32 -> out: (4, 256, 256, 256) f32
// out[b][4*c+k][i][j], k in {ll, lh, hl, hh}
// Memory-bound streaming: 256 MB in + 256 MB out, zero reuse.
// One thread = plane bc, out row i, out cols 4*jq..4*jq+3:
//   reads  2x 16B from input row 2i and row 2i+1 (32 B/lane)
//   writes 1x 16B (nontemporal) into each of the 4 k-planes (16 B/lane,
//   1 KiB contiguous per wave per plane -- the measured-peak store pattern).
//
// NOTE: __builtin_nontemporal_load/store requires a NATIVE clang vector type;
// HIP's float4 is a HIP_vector_type class and is rejected. Use ext_vector_type.

typedef float v4f __attribute__((ext_vector_type(4)));

__global__ __launch_bounds__(256) void haar_dwt_kernel(const float* __restrict__ x,
                                                       float* __restrict__ out) {
    const int t  = blockIdx.x * 256 + threadIdx.x;
    const int jq = t & 63;           // output col quad: cols 4jq .. 4jq+3
    const int i  = (t >> 6) & 255;   // output row
    const int bc = t >> 14;          // b*64 + c, in [0, 256)

    const float* row0 = x + (size_t)bc * (512 * 512) + (2 * i) * 512 + 8 * jq;
    const float* row1 = row0 + 512;

    const v4f r0a = __builtin_nontemporal_load(reinterpret_cast<const v4f*>(row0));
    const v4f r0b = __builtin_nontemporal_load(reinterpret_cast<const v4f*>(row0) + 1);
    const v4f r1a = __builtin_nontemporal_load(reinterpret_cast<const v4f*>(row1));
    const v4f r1b = __builtin_nontemporal_load(reinterpret_cast<const v4f*>(row1) + 1);

    const float half = 0.5f;
    v4f ll, lh, hl, hh;
    // elements 0,1 from r0a/r1a = {a0,b0,a1,b1}/{c0,d0,c1,d1}
    ll[0] = (r0a[0] + r0a[1] + r1a[0] + r1a[1]) * half;
    lh[0] = (r0a[0] - r0a[1] + r1a[0] - r1a[1]) * half;
    hl[0] = (r0a[0] + r0a[1] - r1a[0] - r1a[1]) * half;
    hh[0] = (r0a[0] - r0a[1] - r1a[0] + r1a[1]) * half;
    ll[1] = (r0a[2] + r0a[3] + r1a[2] + r1a[3]) * half;
    lh[1] = (r0a[2] - r0a[3] + r1a[2] - r1a[3]) * half;
    hl[1] = (r0a[2] + r0a[3] - r1a[2] - r1a[3]) * half;
    hh[1] = (r0a[2] - r0a[3] - r1a[2] + r1a[3]) * half;
    // elements 2,3 from r0b/r1b = {a2,b2,a3,b3}/{c2,d2,c3,d3}
    ll[2] = (r0b[0] + r0b[1] + r1b[0] + r1b[1]) * half;
    lh[2] = (r0b[0] - r0b[1] + r1b[0] - r1b[1]) * half;
    hl[2] = (r0b[0] + r0b[1] - r1b[0] - r1b[1]) * half;
    hh[2] = (r0b[0] - r0b[1] - r1b[0] + r1b[1]) * half;
    ll[3] = (r0b[2] + r0b[3] + r1b[2] + r1b[3]) * half;
    lh[3] = (r0b[2] - r0b[3] + r1b[2] - r1b[3]) * half;
    hl[3] = (r0b[2] + r0b[3] - r1b[2] - r1b[3]) * half;
    hh[3] = (r0b[2] - r0b[3] - r1b[2] + r1b[3]) * half;

    // Output: channel = 4*bc + k, each plane 256x256 floats.
    v4f* o = reinterpret_cast<v4f*>(out + ((size_t)(4 * bc) * 256 + i) * 256 + 4 * jq);
    const int plane4 = 256 * 256 / 4;  // 16B-vectors per plane
    __builtin_nontemporal_store(ll, o);
    __builtin_nontemporal_store(lh, o + plane4);
    __builtin_nontemporal_store(hl, o + 2 * plane4);
    __builtin_nontemporal_store(hh, o + 3 * plane4);
}

extern "C" void kernel_launch(void* const* d_in, const int* in_sizes, int n_in,
                              void* d_out, int out_size, void* d_ws, size_t ws_size,
                              hipStream_t stream) {
    const float* x = (const float*)d_in[0];
    float* out = (float*)d_out;
    // total threads = 4*64*256*64 = 4,194,304 -> 16384 blocks of 256 (exact)
    haar_dwt_kernel<<<16384, 256, 0, stream>>>(x, out);
}